// Round 1
// baseline (450.294 us; speedup 1.0000x reference)
//
#include <hip/hip_runtime.h>

// AdderNet forward:  x[256,1,64,64] -> adder(w1)+BN+ReLU -> adder(w2)+BN+ReLU
//                    -> avgpool -> FC -> out[256,10]
// Strategy: never materialize h1 (recompute layer-1 in layer-2's LDS staging);
// materialize a2 (pre-BN layer-2 output) in ws since BN needs batch stats first.
// Stats accumulate as fp32 block partials -> fp64 global atomics (precision).

#define BATCH 256
#define HW 4096

// ---------------- Kernel 1: layer-1 stats (sum, sumsq per channel) ----------
__global__ __launch_bounds__(256) void k_stats1(const float* __restrict__ x,
                                                const float* __restrict__ w1,
                                                double* __restrict__ s1) {
  __shared__ float sx[66 * 66];
  __shared__ float red[4 * 16 * 2];
  int b = blockIdx.x, tid = threadIdx.x;
  const float* xb = x + b * HW;
  for (int i = tid; i < 66 * 66; i += 256) {
    int r = i / 66, cc = i - r * 66;
    int ry = r - 1, rx = cc - 1;
    sx[i] = (ry >= 0 && ry < 64 && rx >= 0 && rx < 64) ? xb[ry * 64 + rx] : 0.f;
  }
  __syncthreads();
  float tsum[16], tsq[16];
#pragma unroll
  for (int c = 0; c < 16; c++) { tsum[c] = 0.f; tsq[c] = 0.f; }
  for (int g = 0; g < 2; g++) {           // 8 channels per pass (register bound)
    float wv[8][9];
#pragma unroll
    for (int c = 0; c < 8; c++)
#pragma unroll
      for (int t = 0; t < 9; t++) wv[c][t] = w1[(g * 8 + c) * 9 + t];
    for (int p = 0; p < 16; p++) {
      int pix = tid + p * 256;
      int y = pix >> 6, xx = pix & 63;
      float pa[9];
#pragma unroll
      for (int dy = 0; dy < 3; dy++)
#pragma unroll
        for (int dx = 0; dx < 3; dx++)
          pa[dy * 3 + dx] = sx[(y + dy) * 66 + xx + dx];
#pragma unroll
      for (int c = 0; c < 8; c++) {
        float acc = 0.f;
#pragma unroll
        for (int t = 0; t < 9; t++) acc += fabsf(pa[t] - wv[c][t]);
        float v = -acc;
        tsum[g * 8 + c] += v;
        tsq[g * 8 + c] += v * v;
      }
    }
  }
  int lane = tid & 63, wid = tid >> 6;
#pragma unroll
  for (int c = 0; c < 16; c++) {
    float s = tsum[c], q = tsq[c];
    for (int off = 32; off; off >>= 1) {
      s += __shfl_down(s, off, 64);
      q += __shfl_down(q, off, 64);
    }
    if (lane == 0) { red[(wid * 16 + c) * 2] = s; red[(wid * 16 + c) * 2 + 1] = q; }
  }
  __syncthreads();
  if (tid < 16) {
    float s = red[tid * 2] + red[(16 + tid) * 2] + red[(32 + tid) * 2] + red[(48 + tid) * 2];
    float q = red[tid * 2 + 1] + red[(16 + tid) * 2 + 1] + red[(32 + tid) * 2 + 1] +
              red[(48 + tid) * 2 + 1];
    atomicAdd(&s1[tid], (double)s);
    atomicAdd(&s1[16 + tid], (double)q);
  }
}

// ---------------- BN affine params: scale = g*rsqrt(var+eps), shift = b-mean*scale
__global__ void k_bnparam(int nc, const double* __restrict__ s,
                          const float* __restrict__ g, const float* __restrict__ bt,
                          float* __restrict__ scale, float* __restrict__ shift) {
  int c = threadIdx.x;
  if (c < nc) {
    double N = 1048576.0;  // 256*64*64
    double mean = s[c] / N;
    double var = s[nc + c] / N - mean * mean;
    float inv = (float)(1.0 / sqrt(var + 1e-5));
    float sc = g[c] * inv;
    scale[c] = sc;
    shift[c] = bt[c] - (float)mean * sc;
  }
}

// ---------------- Kernel 3: layer 2 (the heavy one) -------------------------
// Block = (image b, 8-row band). Recompute h1 tile from x into LDS (BN1+ReLU
// applied), then 4-output-channel register blocking, 2-wide output runs.
__global__ __launch_bounds__(256) void k_layer2(
    const float* __restrict__ x, const float* __restrict__ w1,
    const float* __restrict__ sc1, const float* __restrict__ sf1,
    const float* __restrict__ w2, float* __restrict__ a2,
    double* __restrict__ s2) {
  __shared__ float sxt[12 * 68];       // x tile rows y0-2..y0+9, cols -2..65
  __shared__ float sh[16 * 10 * 66];   // h1 tile [c][row y0-1..y0+8][col -1..64]
  __shared__ float red[4 * 8];
  int blk = blockIdx.x;
  int b = blk >> 3, rb = blk & 7;
  int y0 = rb * 8;
  int tid = threadIdx.x;
  const float* xb = x + b * HW;
  for (int i = tid; i < 12 * 68; i += 256) {
    int r = i / 68, cc = i - r * 68;
    int ry = y0 + r - 2, rx = cc - 2;
    sxt[i] = (ry >= 0 && ry < 64 && rx >= 0 && rx < 64) ? xb[ry * 64 + rx] : 0.f;
  }
  __syncthreads();
  // h1 recompute: same summation order as k_stats1 -> bit-identical values
  for (int c = 0; c < 16; c++) {
    float wv[9];
#pragma unroll
    for (int t = 0; t < 9; t++) wv[t] = w1[c * 9 + t];
    float sc = sc1[c], sf = sf1[c];
    for (int i = tid; i < 660; i += 256) {
      int r = i / 66, col = i - r * 66;
      int y = y0 + r - 1, xx = col - 1;
      float v = 0.f;  // padding of h1 is post-activation zero
      if (y >= 0 && y < 64 && xx >= 0 && xx < 64) {
        float acc = 0.f;
#pragma unroll
        for (int dy = 0; dy < 3; dy++)
#pragma unroll
          for (int dx = 0; dx < 3; dx++)
            acc += fabsf(sxt[(r + dy) * 68 + col + dx] - wv[dy * 3 + dx]);
        v = fmaxf(fmaf(-acc, sc, sf), 0.f);
      }
      sh[c * 660 + i] = v;
    }
  }
  __syncthreads();

  int lane = tid & 63, wid = tid >> 6;
  int x2 = tid & 31, r = tid >> 5;
  int x0 = x2 * 2;
  float* a2b = a2 + (size_t)b * 32 * HW;
  for (int og = 0; og < 8; og++) {
    float acc[4][2];
#pragma unroll
    for (int o = 0; o < 4; o++) { acc[o][0] = 0.f; acc[o][1] = 0.f; }
    for (int c = 0; c < 16; c++) {
      float wv[4][9];
#pragma unroll
      for (int o = 0; o < 4; o++)
#pragma unroll
        for (int t = 0; t < 9; t++)
          wv[o][t] = w2[((og * 4 + o) * 16 + c) * 9 + t];
#pragma unroll
      for (int dy = 0; dy < 3; dy++) {
        int base = c * 660 + (r + dy) * 66 + x0;
        float2 p01 = *(const float2*)&sh[base];
        float2 p23 = *(const float2*)&sh[base + 2];
        float i0 = p01.x, i1 = p01.y, i2 = p23.x, i3 = p23.y;
#pragma unroll
        for (int o = 0; o < 4; o++) {
          acc[o][0] += fabsf(i0 - wv[o][dy * 3]) + fabsf(i1 - wv[o][dy * 3 + 1]) +
                       fabsf(i2 - wv[o][dy * 3 + 2]);
          acc[o][1] += fabsf(i1 - wv[o][dy * 3]) + fabsf(i2 - wv[o][dy * 3 + 1]) +
                       fabsf(i3 - wv[o][dy * 3 + 2]);
        }
      }
    }
    float osum[4], osq[4];
#pragma unroll
    for (int o = 0; o < 4; o++) {
      float v0 = -acc[o][0], v1 = -acc[o][1];
      float2 st; st.x = v0; st.y = v1;
      *(float2*)&a2b[(og * 4 + o) * HW + (y0 + r) * 64 + x0] = st;
      osum[o] = v0 + v1;
      osq[o] = v0 * v0 + v1 * v1;
    }
#pragma unroll
    for (int o = 0; o < 4; o++) {
      float s = osum[o], q = osq[o];
      for (int off = 32; off; off >>= 1) {
        s += __shfl_down(s, off, 64);
        q += __shfl_down(q, off, 64);
      }
      if (lane == 0) { red[wid * 8 + o * 2] = s; red[wid * 8 + o * 2 + 1] = q; }
    }
    __syncthreads();
    if (tid < 8) {
      float v = red[tid] + red[8 + tid] + red[16 + tid] + red[24 + tid];
      int o = og * 4 + (tid >> 1);
      if (tid & 1) atomicAdd(&s2[32 + o], (double)v);
      else         atomicAdd(&s2[o], (double)v);
    }
    __syncthreads();
  }
}

// ---------------- Kernel 5: BN2 + ReLU + avgpool ----------------------------
__global__ __launch_bounds__(256) void k_pool(const float* __restrict__ a2,
                                              const float* __restrict__ sc2,
                                              const float* __restrict__ sf2,
                                              float* __restrict__ pooled) {
  int blk = blockIdx.x;  // b*32 + o
  int o = blk & 31, tid = threadIdx.x;
  const float* p = a2 + (size_t)blk * HW;
  float s = sc2[o], f = sf2[o];
  float acc = 0.f;
#pragma unroll
  for (int i = 0; i < 16; i++) {
    float v = p[tid + i * 256];
    acc += fmaxf(fmaf(v, s, f), 0.f);
  }
  __shared__ float red[4];
  int lane = tid & 63, wid = tid >> 6;
  for (int off = 32; off; off >>= 1) acc += __shfl_down(acc, off, 64);
  if (lane == 0) red[wid] = acc;
  __syncthreads();
  if (tid == 0) pooled[blk] = (red[0] + red[1] + red[2] + red[3]) * (1.f / 4096.f);
}

// ---------------- Kernel 6: FC ----------------------------------------------
__global__ void k_fc(const float* __restrict__ pooled, const float* __restrict__ fw,
                     const float* __restrict__ fb, float* __restrict__ out) {
  int j = blockIdx.x;    // 0..9
  int bb = threadIdx.x;  // 0..255
  float acc = fb[j];
#pragma unroll
  for (int o = 0; o < 32; o++) acc += pooled[bb * 32 + o] * fw[j * 32 + o];
  out[bb * 10 + j] = acc;
}

extern "C" void kernel_launch(void* const* d_in, const int* in_sizes, int n_in,
                              void* d_out, int out_size, void* d_ws, size_t ws_size,
                              hipStream_t stream) {
  const float* x   = (const float*)d_in[0];
  const float* w1  = (const float*)d_in[1];
  const float* g1  = (const float*)d_in[2];
  const float* b1  = (const float*)d_in[3];
  const float* w2  = (const float*)d_in[4];
  const float* g2  = (const float*)d_in[5];
  const float* b2  = (const float*)d_in[6];
  const float* fcw = (const float*)d_in[7];
  const float* fcb = (const float*)d_in[8];
  float* out = (float*)d_out;

  char* ws = (char*)d_ws;
  float* a2 = (float*)ws;                                  // 134,217,728 B
  double* stats = (double*)(ws + 134217728);               // 96 doubles
  double* s1 = stats;                                      // sum[16], sq[16]
  double* s2 = stats + 32;                                 // sum[32], sq[32]
  float* params = (float*)(ws + 134217728 + 768);
  float* sc1 = params, *sf1 = params + 16, *sc2 = params + 32, *sf2 = params + 64;
  float* pooled = (float*)(ws + 134217728 + 768 + 384);    // 8192 floats

  hipMemsetAsync(stats, 0, 768, stream);
  k_stats1<<<256, 256, 0, stream>>>(x, w1, s1);
  k_bnparam<<<1, 64, 0, stream>>>(16, s1, g1, b1, sc1, sf1);
  k_layer2<<<2048, 256, 0, stream>>>(x, w1, sc1, sf1, w2, a2, s2);
  k_bnparam<<<1, 64, 0, stream>>>(32, s2, g2, b2, sc2, sf2);
  k_pool<<<8192, 256, 0, stream>>>(a2, sc2, sf2, pooled);
  k_fc<<<10, 256, 0, stream>>>(pooled, fcw, fcb, out);
}